// Round 3
// baseline (376.426 us; speedup 1.0000x reference)
//
#include <hip/hip_runtime.h>
#include <math.h>

// Problem constants (from reference setup_inputs)
constexpr int B_ = 2048, C_ = 3, T_ = 300, J_ = 25;
constexpr int SLAB = T_ * J_;   // 7500 floats per (b,c) slab, contiguous
constexpr int NBC  = B_ * C_;   // 6144 slabs
constexpr int G    = 8;         // slabs per block
constexpr int NBLK = NBC / G;   // 768 blocks = exactly 3 resident per CU

// 8 slabs per block, barrier-free slab loop. Thread t (t<250) owns 4 FIXED
// columns j=(4t+k)%25 within every slab (per-iter stride 1000 == 0 mod 25),
// accumulates per-slab column partials in registers, flushes with LDS
// atomicAdd into per-(slab,j) bins. ONE barrier per block (vs 2 per slab in
// R1/R2) and 768 instead of 6144 blocks -> kills block-churn overhead and
// gives the compiler 100+ independent float4 loads per thread to pipeline.
__global__ __launch_bounds__(256, 3) void fused_kernel(
    const float* __restrict__ gin, const float* __restrict__ gtg,
    float* __restrict__ rec_part, float* __restrict__ sm_part) {
  __shared__ float s_col[G * J_];   // per-(slab-in-block, j) column sums
  __shared__ float s_red[4];

  const int tid  = threadIdx.x;
  const int lane = tid & 63;
  const int wave = tid >> 6;

  for (int i = tid; i < G * J_; i += 256) s_col[i] = 0.f;
  __syncthreads();  // bin init visible before atomics

  const int slab0 = blockIdx.x * G;
  const int e0    = tid * 4;
  float rec = 0.f;

  if (tid < 250) {
    // Fixed column ids and boundary masks (same for every slab).
    const int b0 = e0 % 25, b1 = (e0 + 1) % 25, b2 = (e0 + 2) % 25, b3 = (e0 + 3) % 25;
    const bool q0 = (e0    ) >= 25, q1 = (e0 + 1) >= 25,   // chunk-0 quad mask (t>0)
               q2 = (e0 + 2) >= 25, q3 = (e0 + 3) >= 25;
    const bool l0 = (e0    ) < 475, l1 = (e0 + 1) < 475,   // chunk-7 lin mask (t<299)
               l2 = (e0 + 2) < 475, l3 = (e0 + 3) < 475;

    #pragma unroll
    for (int g = 0; g < G; ++g) {
      const size_t base = (size_t)(slab0 + g) * SLAB;
      const float* in = gin + base;
      const float* tg = gtg + base;
      float c0 = 0.f, c1 = 0.f, c2 = 0.f, c3 = 0.f;

      // chunk 0 (e in [0,1000)): lin always on, quad masked
      {
        const float4 x = *(const float4*)(in + e0);
        const float4 y = *(const float4*)(tg + e0);
        float d, s;
        d = x.x - y.x; s = x.x + y.x; rec += d * d; c0 += d - (q0 ? d * s : 0.f);
        d = x.y - y.y; s = x.y + y.y; rec += d * d; c1 += d - (q1 ? d * s : 0.f);
        d = x.z - y.z; s = x.z + y.z; rec += d * d; c2 += d - (q2 ? d * s : 0.f);
        d = x.w - y.w; s = x.w + y.w; rec += d * d; c3 += d - (q3 ? d * s : 0.f);
      }
      // chunks 1..6: interior, no masks: c += d*(1-s)
      #pragma unroll
      for (int it = 1; it < 7; ++it) {
        const int e = it * 1000 + e0;
        const float4 x = *(const float4*)(in + e);
        const float4 y = *(const float4*)(tg + e);
        float d, s;
        d = x.x - y.x; s = x.x + y.x; rec += d * d; c0 += d * (1.f - s);
        d = x.y - y.y; s = x.y + y.y; rec += d * d; c1 += d * (1.f - s);
        d = x.z - y.z; s = x.z + y.z; rec += d * d; c2 += d * (1.f - s);
        d = x.w - y.w; s = x.w + y.w; rec += d * d; c3 += d * (1.f - s);
      }
      // chunk 7 (e in [7000,7500)): only tid<125; quad always on, lin masked
      if (tid < 125) {
        const int e = 7000 + e0;
        const float4 x = *(const float4*)(in + e);
        const float4 y = *(const float4*)(tg + e);
        float d, s;
        d = x.x - y.x; s = x.x + y.x; rec += d * d; c0 += (l0 ? d : 0.f) - d * s;
        d = x.y - y.y; s = x.y + y.y; rec += d * d; c1 += (l1 ? d : 0.f) - d * s;
        d = x.z - y.z; s = x.z + y.z; rec += d * d; c2 += (l2 ? d : 0.f) - d * s;
        d = x.w - y.w; s = x.w + y.w; rec += d * d; c3 += (l3 ? d : 0.f) - d * s;
      }
      atomicAdd(&s_col[g * 25 + b0], c0);
      atomicAdd(&s_col[g * 25 + b1], c1);
      atomicAdd(&s_col[g * 25 + b2], c2);
      atomicAdd(&s_col[g * 25 + b3], c3);
    }
  }

  // rec: wave shuffle reduce
  #pragma unroll
  for (int off = 32; off > 0; off >>= 1) rec += __shfl_down(rec, off, 64);
  if (lane == 0) s_red[wave] = rec;
  __syncthreads();  // the ONLY post-loop barrier: covers s_red and all bin atomics

  // smooth finalize: wave w handles slabs g = w, w+4
  #pragma unroll
  for (int g = wave; g < G; g += 4) {
    float v = (lane < J_ - 1) ? fabsf(s_col[g * 25 + lane]) : 0.f;  // j<24 only
    #pragma unroll
    for (int off = 32; off > 0; off >>= 1) v += __shfl_down(v, off, 64);
    if (lane == 0) sm_part[slab0 + g] = sqrtf(v);
  }
  if (tid == 0)
    rec_part[blockIdx.x] = s_red[0] + s_red[1] + s_red[2] + s_red[3];
}

__global__ __launch_bounds__(256) void finalize_kernel(
    const float* __restrict__ rec_part, const float* __restrict__ sm_part,
    float* __restrict__ out) {
  const int tid  = threadIdx.x;
  const int lane = tid & 63;
  const int wave = tid >> 6;
  double r = 0.0, s = 0.0;
  for (int i = tid; i < NBLK; i += 256) r += (double)rec_part[i];
  for (int i = tid; i < NBC;  i += 256) s += (double)sm_part[i];
  #pragma unroll
  for (int off = 32; off > 0; off >>= 1) {
    r += __shfl_down(r, off, 64);
    s += __shfl_down(s, off, 64);
  }
  __shared__ double sr[4], ss[4];
  if (lane == 0) { sr[wave] = r; ss[wave] = s; }
  __syncthreads();
  if (tid == 0) {
    const double rt = sr[0] + sr[1] + sr[2] + sr[3];
    const double st = ss[0] + ss[1] + ss[2] + ss[3];
    const double loss_rec    = rt / (double)((long long)B_ * C_ * T_ * J_);
    const double loss_smooth = (st / (double)NBC) / (double)(J_ * T_);
    out[0] = (float)(2.0 * loss_rec + 3.0 * loss_smooth);
  }
}

extern "C" void kernel_launch(void* const* d_in, const int* in_sizes, int n_in,
                              void* d_out, int out_size, void* d_ws, size_t ws_size,
                              hipStream_t stream) {
  const float* in = (const float*)d_in[0];
  const float* tg = (const float*)d_in[1];
  float* rec_part = (float*)d_ws;        // NBLK floats
  float* sm_part  = rec_part + NBLK;     // NBC floats
  fused_kernel<<<NBLK, 256, 0, stream>>>(in, tg, rec_part, sm_part);
  finalize_kernel<<<1, 256, 0, stream>>>(rec_part, sm_part, (float*)d_out);
}

// Round 5
// 338.281 us; speedup vs baseline: 1.1128x; 1.1128x over previous
//
#include <hip/hip_runtime.h>
#include <math.h>

// Problem constants (from reference setup_inputs)
constexpr int B_ = 2048, C_ = 3, T_ = 300, J_ = 25;
constexpr int SLAB = T_ * J_;   // 7500 floats per (b,c) slab, contiguous
constexpr int NBC  = B_ * C_;   // 6144 slabs
constexpr int G    = 8;         // slabs per block
constexpr int NBLK = NBC / G;   // 768 blocks = exactly 3 resident per CU

// Native clang vector (NOT HIP_vector_type) — required by the nontemporal builtin.
typedef float fx4 __attribute__((ext_vector_type(4)));

// Non-temporal 16B load: global_load_dwordx4 ... nt — bypass L2/L3 allocation
// for these use-once streams (theory: cache fill path is the ~2.9 TB/s wall).
__device__ __forceinline__ fx4 ldnt4(const float* p) {
  return __builtin_nontemporal_load(reinterpret_cast<const fx4*>(p));
}

// Fixed-column register scheme (thread t<250 owns j=(4t+k)%25 at per-iter
// stride 1000 == 0 mod 25). All slab loads issued into register arrays
// BEFORE compute (~16 nt loads in flight/thread).
__global__ __launch_bounds__(256, 3) void fused_kernel(
    const float* __restrict__ gin, const float* __restrict__ gtg,
    float* __restrict__ rec_part, float* __restrict__ sm_part) {
  __shared__ float s_col[G * J_];   // per-(slab-in-block, j) column sums
  __shared__ float s_red[4];

  const int tid  = threadIdx.x;
  const int lane = tid & 63;
  const int wave = tid >> 6;

  for (int i = tid; i < G * J_; i += 256) s_col[i] = 0.f;
  __syncthreads();  // bin init visible before atomics

  const int slab0 = blockIdx.x * G;
  const int e0    = tid * 4;
  float rec = 0.f;

  if (tid < 250) {
    const int b0 = e0 % 25, b1 = (e0 + 1) % 25, b2 = (e0 + 2) % 25, b3 = (e0 + 3) % 25;
    const bool q0 = (e0    ) >= 25, q1 = (e0 + 1) >= 25,   // chunk-0 quad mask (t>0)
               q2 = (e0 + 2) >= 25, q3 = (e0 + 3) >= 25;
    const bool l0 = (e0    ) < 475, l1 = (e0 + 1) < 475,   // chunk-7 lin mask (t<299)
               l2 = (e0 + 2) < 475, l3 = (e0 + 3) < 475;
    const bool tail = (tid < 125);

    #pragma unroll
    for (int g = 0; g < G; ++g) {
      const size_t base = (size_t)(slab0 + g) * SLAB;
      const float* in = gin + base;
      const float* tg = gtg + base;

      // ---- issue ALL loads for this slab first (force MLP) ----
      fx4 xv[8], yv[8];
      #pragma unroll
      for (int it = 0; it < 7; ++it) {
        xv[it] = ldnt4(in + it * 1000 + e0);
        yv[it] = ldnt4(tg + it * 1000 + e0);
      }
      if (tail) {             // chunk 7: e in [7000,7500), only tid<125
        xv[7] = ldnt4(in + 7000 + e0);
        yv[7] = ldnt4(tg + 7000 + e0);
      }

      // ---- compute ----
      float c0 = 0.f, c1 = 0.f, c2 = 0.f, c3 = 0.f;
      {  // chunk 0: lin always on, quad masked
        float d, s;
        d = xv[0].x - yv[0].x; s = xv[0].x + yv[0].x; rec += d * d; c0 += d - (q0 ? d * s : 0.f);
        d = xv[0].y - yv[0].y; s = xv[0].y + yv[0].y; rec += d * d; c1 += d - (q1 ? d * s : 0.f);
        d = xv[0].z - yv[0].z; s = xv[0].z + yv[0].z; rec += d * d; c2 += d - (q2 ? d * s : 0.f);
        d = xv[0].w - yv[0].w; s = xv[0].w + yv[0].w; rec += d * d; c3 += d - (q3 ? d * s : 0.f);
      }
      #pragma unroll
      for (int it = 1; it < 7; ++it) {  // interior: c += d*(1-s)
        float d, s;
        d = xv[it].x - yv[it].x; s = xv[it].x + yv[it].x; rec += d * d; c0 += d * (1.f - s);
        d = xv[it].y - yv[it].y; s = xv[it].y + yv[it].y; rec += d * d; c1 += d * (1.f - s);
        d = xv[it].z - yv[it].z; s = xv[it].z + yv[it].z; rec += d * d; c2 += d * (1.f - s);
        d = xv[it].w - yv[it].w; s = xv[it].w + yv[it].w; rec += d * d; c3 += d * (1.f - s);
      }
      if (tail) {  // chunk 7: quad always on, lin masked
        float d, s;
        d = xv[7].x - yv[7].x; s = xv[7].x + yv[7].x; rec += d * d; c0 += (l0 ? d : 0.f) - d * s;
        d = xv[7].y - yv[7].y; s = xv[7].y + yv[7].y; rec += d * d; c1 += (l1 ? d : 0.f) - d * s;
        d = xv[7].z - yv[7].z; s = xv[7].z + yv[7].z; rec += d * d; c2 += (l2 ? d : 0.f) - d * s;
        d = xv[7].w - yv[7].w; s = xv[7].w + yv[7].w; rec += d * d; c3 += (l3 ? d : 0.f) - d * s;
      }
      atomicAdd(&s_col[g * 25 + b0], c0);
      atomicAdd(&s_col[g * 25 + b1], c1);
      atomicAdd(&s_col[g * 25 + b2], c2);
      atomicAdd(&s_col[g * 25 + b3], c3);
    }
  }

  // rec: wave shuffle reduce
  #pragma unroll
  for (int off = 32; off > 0; off >>= 1) rec += __shfl_down(rec, off, 64);
  if (lane == 0) s_red[wave] = rec;
  __syncthreads();  // covers s_red and all bin atomics

  // smooth finalize: wave w handles slabs g = w, w+4
  #pragma unroll
  for (int g = wave; g < G; g += 4) {
    float v = (lane < J_ - 1) ? fabsf(s_col[g * 25 + lane]) : 0.f;  // j<24 only
    #pragma unroll
    for (int off = 32; off > 0; off >>= 1) v += __shfl_down(v, off, 64);
    if (lane == 0) sm_part[slab0 + g] = sqrtf(v);
  }
  if (tid == 0)
    rec_part[blockIdx.x] = s_red[0] + s_red[1] + s_red[2] + s_red[3];
}

__global__ __launch_bounds__(256) void finalize_kernel(
    const float* __restrict__ rec_part, const float* __restrict__ sm_part,
    float* __restrict__ out) {
  const int tid  = threadIdx.x;
  const int lane = tid & 63;
  const int wave = tid >> 6;
  double r = 0.0, s = 0.0;
  for (int i = tid; i < NBLK; i += 256) r += (double)rec_part[i];
  for (int i = tid; i < NBC;  i += 256) s += (double)sm_part[i];
  #pragma unroll
  for (int off = 32; off > 0; off >>= 1) {
    r += __shfl_down(r, off, 64);
    s += __shfl_down(s, off, 64);
  }
  __shared__ double sr[4], ss[4];
  if (lane == 0) { sr[wave] = r; ss[wave] = s; }
  __syncthreads();
  if (tid == 0) {
    const double rt = sr[0] + sr[1] + sr[2] + sr[3];
    const double st = ss[0] + ss[1] + ss[2] + ss[3];
    const double loss_rec    = rt / (double)((long long)B_ * C_ * T_ * J_);
    const double loss_smooth = (st / (double)NBC) / (double)(J_ * T_);
    out[0] = (float)(2.0 * loss_rec + 3.0 * loss_smooth);
  }
}

extern "C" void kernel_launch(void* const* d_in, const int* in_sizes, int n_in,
                              void* d_out, int out_size, void* d_ws, size_t ws_size,
                              hipStream_t stream) {
  const float* in = (const float*)d_in[0];
  const float* tg = (const float*)d_in[1];
  float* rec_part = (float*)d_ws;        // NBLK floats
  float* sm_part  = rec_part + NBLK;     // NBC floats
  fused_kernel<<<NBLK, 256, 0, stream>>>(in, tg, rec_part, sm_part);
  finalize_kernel<<<1, 256, 0, stream>>>(rec_part, sm_part, (float*)d_out);
}